// Round 3
// baseline (101.288 us; speedup 1.0000x reference)
//
#include <hip/hip_runtime.h>
#include <math.h>

#define NTOK 8192
#define DIMV 512
#define CD 13
#define KSZ 8192

#define PC_OFF (NTOK * CD * 4)            /* 425984: per-block cm/pe pairs   */
#define E_OFF  (PC_OFF + 512 * 2 * 4)     /* 430080: k3 per-block entropy    */
#define C_OFF  (E_OFF + 256)              /* 430336 (16B aligned): partial C */

// ---------------------------------------------------------------------------
// K1 (fused): h = x @ w_in + b_in (f32 per-lane partial, f64 cross-lane sum),
// indices, commit & per-sample-entropy per-block partials (plain stores),
// h -> ws, and out = sign(h) @ w_out + b_out.
// 16 lanes per token, 4 tokens per wave, 16 tokens per block, 512 blocks.
// ---------------------------------------------------------------------------
__global__ __launch_bounds__(256) void k1_fused(const float* __restrict__ x,
                                                const float* __restrict__ w_in,
                                                const float* __restrict__ b_in,
                                                const float* __restrict__ w_out,
                                                const float* __restrict__ b_out,
                                                float* __restrict__ ws_h,
                                                float* __restrict__ ws_pc,
                                                float* __restrict__ outv,
                                                float* __restrict__ out_ind) {
  __shared__ __align__(16) float s_winT[CD * DIMV];  // transposed [c][d]
  __shared__ __align__(16) float s_wout[CD * DIMV];  // row-major [c][d]
  __shared__ float s_cm[16], s_pe[16];
  int t = threadIdx.x;
  for (int g = t; g < CD * DIMV; g += 256) {
    int d = g / CD, c = g - d * CD;
    s_winT[c * DIMV + d] = w_in[g];
    s_wout[g] = w_out[g];
  }
  __syncthreads();

  int lane = t & 63;
  int wave = t >> 6;
  int l15 = lane & 15;
  int grp = lane >> 4;
  int n = blockIdx.x * 16 + wave * 4 + grp;

  const float4* x4 = (const float4*)(x + (size_t)n * DIMV);

  // per-lane f32 partial over 32 elements of d
  float facc[CD];
#pragma unroll
  for (int c = 0; c < CD; ++c) facc[c] = 0.f;
#pragma unroll
  for (int j = 0; j < 8; ++j) {
    float4 xv = x4[l15 + j * 16];
    int dbase = (l15 + j * 16) * 4;
#pragma unroll
    for (int c = 0; c < CD; ++c) {
      const float4 wv = *(const float4*)&s_winT[c * DIMV + dbase];
      facc[c] += xv.x * wv.x + xv.y * wv.y + xv.z * wv.z + xv.w * wv.w;
    }
  }
  // f64 butterfly across the 16-lane group; every lane ends with all 13 h's
  double acc[CD];
#pragma unroll
  for (int c = 0; c < CD; ++c) {
    double a = (double)facc[c];
    a += __shfl_xor(a, 1, 64);
    a += __shfl_xor(a, 2, 64);
    a += __shfl_xor(a, 4, 64);
    a += __shfl_xor(a, 8, 64);
    acc[c] = a + (double)b_in[c];
  }

  // index (all lanes compute; group leader stores)
  int idx = 0;
#pragma unroll
  for (int c = 0; c < CD; ++c) idx |= (acc[c] > 0.0 ? 1 : 0) << (12 - c);
  if (l15 == 0) out_ind[n] = (float)idx;

  // h store + commit/entropy: lane l15 owns channel c==l15 (static indexing)
  float hv = 0.f;
#pragma unroll
  for (int c = 0; c < CD; ++c) {
    if (l15 == c) {
      float h32 = (float)acc[c];
      ws_h[(size_t)n * CD + c] = h32;
      hv = h32;
    }
  }
  float cm = 0.f, pe = 0.f;
  if (l15 < CD) {
    float a = fabsf(hv);
    float d1 = a - 1.f;
    cm = d1 * d1;                       // (h - sign(h))^2 == (|h|-1)^2
    float z = 4.f * a;                  // binary entropy of sigmoid(4h)
    float e = expf(-z);
    pe = log1pf(e) + z * e / (1.f + e);
  }
  cm += __shfl_xor(cm, 1, 64); pe += __shfl_xor(pe, 1, 64);
  cm += __shfl_xor(cm, 2, 64); pe += __shfl_xor(pe, 2, 64);
  cm += __shfl_xor(cm, 4, 64); pe += __shfl_xor(pe, 4, 64);
  cm += __shfl_xor(cm, 8, 64); pe += __shfl_xor(pe, 8, 64);
  if (l15 == 0) { s_cm[wave * 4 + grp] = cm; s_pe[wave * 4 + grp] = pe; }

  // out = sign(h) @ w_out + b_out; wave covers 512 outputs of its 4 tokens
  int dpos = lane * 4;
  float4 bo0 = *(const float4*)(b_out + dpos);
  float4 bo1 = *(const float4*)(b_out + dpos + 256);
  int n0 = blockIdx.x * 16 + wave * 4;
#pragma unroll
  for (int tt = 0; tt < 4; ++tt) {
    int id2 = __shfl(idx, tt * 16, 64);
    float4 o0 = bo0, o1 = bo1;
#pragma unroll
    for (int c = 0; c < CD; ++c) {
      float sgn = ((id2 >> (12 - c)) & 1) ? 1.f : -1.f;
      const float4 w0 = *(const float4*)&s_wout[c * DIMV + dpos];
      const float4 w1 = *(const float4*)&s_wout[c * DIMV + dpos + 256];
      o0.x = fmaf(sgn, w0.x, o0.x); o0.y = fmaf(sgn, w0.y, o0.y);
      o0.z = fmaf(sgn, w0.z, o0.z); o0.w = fmaf(sgn, w0.w, o0.w);
      o1.x = fmaf(sgn, w1.x, o1.x); o1.y = fmaf(sgn, w1.y, o1.y);
      o1.z = fmaf(sgn, w1.z, o1.z); o1.w = fmaf(sgn, w1.w, o1.w);
    }
    float4* dst = (float4*)(outv + (size_t)(n0 + tt) * DIMV);
    dst[lane] = o0;
    dst[lane + 64] = o1;
  }

  __syncthreads();
  if (t == 0) {
    float C = 0.f, P = 0.f;
#pragma unroll
    for (int i = 0; i < 16; ++i) { C += s_cm[i]; P += s_pe[i]; }
    ws_pc[blockIdx.x * 2] = C;
    ws_pc[blockIdx.x * 2 + 1] = P;
  }
}

// ---------------------------------------------------------------------------
// K2: avg_probs partials via rank-1 factorization. probs[n] = A[64] ⊗ B[128].
// One wave per token-iteration; sB write->read is same-wave (lgkmcnt-ordered,
// no barrier). Lane l owns khi=l; acc[128] over klo. Block partial -> ws_C.
// ---------------------------------------------------------------------------
__global__ __launch_bounds__(256) void k2_avgp(const float* __restrict__ ws_h,
                                               float* __restrict__ ws_C,
                                               int tokens_per_block) {
  __shared__ __align__(16) float sB[4][128];
  __shared__ __align__(16) float sC[KSZ];
  int t = threadIdx.x;
  int lane = t & 63;
  int wave = t >> 6;

  float acc[128];
#pragma unroll
  for (int i = 0; i < 128; ++i) acc[i] = 0.f;

  int n0 = blockIdx.x * tokens_per_block;
  for (int tt = wave; tt < tokens_per_block; tt += 4) {
    int n = n0 + tt;
    float p[CD], q[CD];
#pragma unroll
    for (int c = 0; c < CD; ++c) {
      float hvv = ws_h[(size_t)n * CD + c];
      float e = expf(-4.f * hvv);
      float r = 1.f / (1.f + e);
      p[c] = r;           // P(bit c = 1)
      q[c] = e * r;       // P(bit c = 0)
    }
    float A = ((lane >> 5) & 1) ? p[0] : q[0];
    A *= ((lane >> 4) & 1) ? p[1] : q[1];
    A *= ((lane >> 3) & 1) ? p[2] : q[2];
    A *= ((lane >> 2) & 1) ? p[3] : q[3];
    A *= ((lane >> 1) & 1) ? p[4] : q[4];
    A *= (lane & 1) ? p[5] : q[5];
    float Bb = ((lane >> 5) & 1) ? p[7] : q[7];
    Bb *= ((lane >> 4) & 1) ? p[8] : q[8];
    Bb *= ((lane >> 3) & 1) ? p[9] : q[9];
    Bb *= ((lane >> 2) & 1) ? p[10] : q[10];
    Bb *= ((lane >> 1) & 1) ? p[11] : q[11];
    Bb *= (lane & 1) ? p[12] : q[12];
    sB[wave][lane] = q[6] * Bb;        // klo = lane
    sB[wave][64 + lane] = p[6] * Bb;   // klo = lane + 64
    const float4* B4 = (const float4*)sB[wave];
#pragma unroll
    for (int kk = 0; kk < 32; ++kk) {
      float4 b = B4[kk];
      acc[kk * 4 + 0] = fmaf(A, b.x, acc[kk * 4 + 0]);
      acc[kk * 4 + 1] = fmaf(A, b.y, acc[kk * 4 + 1]);
      acc[kk * 4 + 2] = fmaf(A, b.z, acc[kk * 4 + 2]);
      acc[kk * 4 + 3] = fmaf(A, b.w, acc[kk * 4 + 3]);
    }
  }

  // block reduce into sC[klo*64 + khi] (permutation of k; entropy invariant)
  for (int w = 0; w < 4; ++w) {
    if (wave == w) {
#pragma unroll
      for (int i = 0; i < 128; ++i) {
        if (w == 0) sC[i * 64 + lane] = acc[i];
        else        sC[i * 64 + lane] += acc[i];
      }
    }
    __syncthreads();
  }
  float4* dst = (float4*)(ws_C + (size_t)blockIdx.x * KSZ);
  const float4* src = (const float4*)sC;
  for (int i = t; i < KSZ / 4; i += 256) dst[i] = src[i];
}

// ---------------------------------------------------------------------------
// K3: reduce nparts partial C's -> per-block entropy partial (plain store).
// 64 blocks x 128 slots each.
// ---------------------------------------------------------------------------
__global__ __launch_bounds__(256) void k3_cbent(const float* __restrict__ ws_C,
                                                float* __restrict__ ws_e,
                                                int nparts) {
  __shared__ float red[256];
  __shared__ float s2[2];
  int t = threadIdx.x;
  int s = blockIdx.x * 128 + (t & 127);
  int pg = t >> 7;
  float sum = 0.f;
  for (int p = pg; p < nparts; p += 2) sum += ws_C[(size_t)p * KSZ + s];
  red[t] = sum;
  __syncthreads();
  float contrib = 0.f;
  if (t < 128) {
    float v = red[t] + red[t + 128];
    float avg = v * (1.f / (float)NTOK);
    contrib = -avg * logf(avg + 1e-5f);
  }
  contrib += __shfl_xor(contrib, 1, 64);
  contrib += __shfl_xor(contrib, 2, 64);
  contrib += __shfl_xor(contrib, 4, 64);
  contrib += __shfl_xor(contrib, 8, 64);
  contrib += __shfl_xor(contrib, 16, 64);
  contrib += __shfl_xor(contrib, 32, 64);
  if ((t & 63) == 0 && t < 128) s2[t >> 6] = contrib;
  __syncthreads();
  if (t == 0) ws_e[blockIdx.x] = s2[0] + s2[1];
}

// ---------------------------------------------------------------------------
// K4: final assembly (single block, deterministic fixed-order sums).
// ---------------------------------------------------------------------------
__global__ __launch_bounds__(256) void k4_final(const float* __restrict__ ws_pc,
                                                const float* __restrict__ ws_e,
                                                float* __restrict__ d_aux) {
  __shared__ float rc[256], rp[256], re[256];
  int t = threadIdx.x;
  float cm = 0.f, pe = 0.f, eb = 0.f;
  for (int i = t; i < 512; i += 256) { cm += ws_pc[2 * i]; pe += ws_pc[2 * i + 1]; }
  if (t < 64) eb = ws_e[t];
  rc[t] = cm; rp[t] = pe; re[t] = eb;
  __syncthreads();
  if (t == 0) {
    float C = 0.f, P = 0.f, E = 0.f;
    for (int i = 0; i < 256; ++i) { C += rc[i]; P += rp[i]; }
    for (int i = 0; i < 64; ++i) E += re[i];
    float commit = C * (1.f / (float)(NTOK * CD));
    float psE = P * (1.f / (float)NTOK);
    d_aux[0] = 0.1f * (psE - E) + 0.25f * commit;
  }
}

extern "C" void kernel_launch(void* const* d_in, const int* in_sizes, int n_in,
                              void* d_out, int out_size, void* d_ws, size_t ws_size,
                              hipStream_t stream) {
  const float* x     = (const float*)d_in[0];
  const float* w_in  = (const float*)d_in[1];
  const float* b_in  = (const float*)d_in[2];
  const float* w_out = (const float*)d_in[3];
  const float* b_out = (const float*)d_in[4];
  // d_in[5] = codebook (unused: codes are the 13-bit sign patterns)

  float* outv = (float*)d_out;                       // [4*2048*512]
  float* ind  = outv + (size_t)NTOK * DIMV;          // [8192] as float
  float* aux  = ind + NTOK;                          // [1]

  float* ws_h  = (float*)d_ws;
  float* ws_pc = (float*)((char*)d_ws + PC_OFF);
  float* ws_e  = (float*)((char*)d_ws + E_OFF);
  float* ws_C  = (float*)((char*)d_ws + C_OFF);

  int nparts = 64;
  while (nparts > 8 && (size_t)C_OFF + (size_t)nparts * KSZ * 4 > ws_size)
    nparts >>= 1;

  k1_fused<<<NTOK / 16, 256, 0, stream>>>(x, w_in, b_in, w_out, b_out,
                                          ws_h, ws_pc, outv, ind);
  k2_avgp<<<nparts, 256, 0, stream>>>(ws_h, ws_C, NTOK / nparts);
  k3_cbent<<<64, 256, 0, stream>>>(ws_C, ws_e, nparts);
  k4_final<<<1, 256, 0, stream>>>(ws_pc, ws_e, aux);
}

// Round 4
// 55.486 us; speedup vs baseline: 1.8255x; 1.8255x over previous
//
#include <hip/hip_runtime.h>
#include <math.h>

#define NTOK 8192
#define DIMV 512
#define CD 13
#define KSZ 8192

#define PC_OFF (NTOK * CD * 4)            /* 425984: per-block cm/pe pairs (512x2) */
#define E_OFF  (PC_OFF + 4096)            /* 430080: k3 per-block entropy (256)    */
#define C_OFF  (E_OFF + 1024)             /* 431104 (16B aligned): partial C       */

// ---------------------------------------------------------------------------
// K1 (fused): h = x @ w_in + b_in (f32 per-lane partial, f64 cross-lane sum),
// indices, commit & per-sample-entropy per-block partials, h -> ws,
// out = sign(h) @ w_out + b_out (c-outer loop: 4x fewer LDS reads).
// 16 lanes per token, 4 tokens per wave, 16 tokens per block, 512 blocks.
// ---------------------------------------------------------------------------
__global__ __launch_bounds__(256) void k1_fused(const float* __restrict__ x,
                                                const float* __restrict__ w_in,
                                                const float* __restrict__ b_in,
                                                const float* __restrict__ w_out,
                                                const float* __restrict__ b_out,
                                                float* __restrict__ ws_h,
                                                float* __restrict__ ws_pc,
                                                float* __restrict__ outv,
                                                float* __restrict__ out_ind) {
  __shared__ __align__(16) float s_winT[CD * DIMV];  // transposed [c][d]
  __shared__ __align__(16) float s_wout[CD * DIMV];  // row-major [c][d]
  __shared__ float s_cm[16], s_pe[16];
  int t = threadIdx.x;
  for (int g = t; g < CD * DIMV; g += 256) {
    int d = g / CD, c = g - d * CD;
    s_winT[c * DIMV + d] = w_in[g];
    s_wout[g] = w_out[g];
  }
  __syncthreads();

  int lane = t & 63;
  int wave = t >> 6;
  int l15 = lane & 15;
  int grp = lane >> 4;
  int n = blockIdx.x * 16 + wave * 4 + grp;

  const float4* x4 = (const float4*)(x + (size_t)n * DIMV);

  // per-lane f32 partial over 32 elements of d
  float facc[CD];
#pragma unroll
  for (int c = 0; c < CD; ++c) facc[c] = 0.f;
#pragma unroll
  for (int j = 0; j < 8; ++j) {
    float4 xv = x4[l15 + j * 16];
    int dbase = (l15 + j * 16) * 4;
#pragma unroll
    for (int c = 0; c < CD; ++c) {
      const float4 wv = *(const float4*)&s_winT[c * DIMV + dbase];
      facc[c] += xv.x * wv.x + xv.y * wv.y + xv.z * wv.z + xv.w * wv.w;
    }
  }
  // f64 butterfly across the 16-lane group; every lane ends with all 13 h's
  double acc[CD];
#pragma unroll
  for (int c = 0; c < CD; ++c) {
    double a = (double)facc[c];
    a += __shfl_xor(a, 1, 64);
    a += __shfl_xor(a, 2, 64);
    a += __shfl_xor(a, 4, 64);
    a += __shfl_xor(a, 8, 64);
    acc[c] = a + (double)b_in[c];
  }

  // index (all lanes of group compute identically)
  int idx = 0;
#pragma unroll
  for (int c = 0; c < CD; ++c) idx |= (acc[c] > 0.0 ? 1 : 0) << (12 - c);
  if (l15 == 0) out_ind[n] = (float)idx;

  // h store: lane l15 owns channel c==l15 (static select chain, one store)
  float hv = 0.f;
#pragma unroll
  for (int c = 0; c < CD; ++c) if (l15 == c) hv = (float)acc[c];
  float cm = 0.f, pe = 0.f;
  if (l15 < CD) {
    ws_h[(size_t)n * CD + l15] = hv;
    float a = fabsf(hv);
    float d1 = a - 1.f;
    cm = d1 * d1;                       // (h - sign(h))^2 == (|h|-1)^2
    float z = 4.f * a;                  // binary entropy of sigmoid(4h)
    float e = expf(-z);
    pe = log1pf(e) + z * e / (1.f + e);
  }
  cm += __shfl_xor(cm, 1, 64); pe += __shfl_xor(pe, 1, 64);
  cm += __shfl_xor(cm, 2, 64); pe += __shfl_xor(pe, 2, 64);
  cm += __shfl_xor(cm, 4, 64); pe += __shfl_xor(pe, 4, 64);
  cm += __shfl_xor(cm, 8, 64); pe += __shfl_xor(pe, 8, 64);
  if (l15 == 0) { s_cm[wave * 4 + grp] = cm; s_pe[wave * 4 + grp] = pe; }

  // out = sign(h) @ w_out + b_out; c-outer so each w_out float4 serves 4 tokens
  int dpos = lane * 4;
  int id2[4];
#pragma unroll
  for (int tt = 0; tt < 4; ++tt) id2[tt] = __shfl(idx, tt * 16, 64);
  float4 o[4][2];
  {
    float4 bo0 = *(const float4*)(b_out + dpos);
    float4 bo1 = *(const float4*)(b_out + dpos + 256);
#pragma unroll
    for (int tt = 0; tt < 4; ++tt) { o[tt][0] = bo0; o[tt][1] = bo1; }
  }
#pragma unroll
  for (int c = 0; c < CD; ++c) {
    const float4 w0 = *(const float4*)&s_wout[c * DIMV + dpos];
    const float4 w1 = *(const float4*)&s_wout[c * DIMV + dpos + 256];
#pragma unroll
    for (int tt = 0; tt < 4; ++tt) {
      float sgn = ((id2[tt] >> (12 - c)) & 1) ? 1.f : -1.f;
      o[tt][0].x = fmaf(sgn, w0.x, o[tt][0].x);
      o[tt][0].y = fmaf(sgn, w0.y, o[tt][0].y);
      o[tt][0].z = fmaf(sgn, w0.z, o[tt][0].z);
      o[tt][0].w = fmaf(sgn, w0.w, o[tt][0].w);
      o[tt][1].x = fmaf(sgn, w1.x, o[tt][1].x);
      o[tt][1].y = fmaf(sgn, w1.y, o[tt][1].y);
      o[tt][1].z = fmaf(sgn, w1.z, o[tt][1].z);
      o[tt][1].w = fmaf(sgn, w1.w, o[tt][1].w);
    }
  }
  int n0 = blockIdx.x * 16 + wave * 4;
#pragma unroll
  for (int tt = 0; tt < 4; ++tt) {
    float4* dst = (float4*)(outv + (size_t)(n0 + tt) * DIMV);
    dst[lane] = o[tt][0];
    dst[lane + 64] = o[tt][1];
  }

  __syncthreads();
  if (t == 0) {
    float C = 0.f, P = 0.f;
#pragma unroll
    for (int i = 0; i < 16; ++i) { C += s_cm[i]; P += s_pe[i]; }
    ws_pc[blockIdx.x * 2] = C;
    ws_pc[blockIdx.x * 2 + 1] = P;
  }
}

// ---------------------------------------------------------------------------
// K2: avg_probs partials. probs[n] = A[64] ⊗ B[128] (rank-1, 13 Bernoullis).
// Phase 1: waves compute per-token A (parity-split) and B into LDS.
// Phase 2: thread t owns slots s = t + 256*j (j=0..31); per token: one scalar
// B read + 8 uniform float4 A reads + 32 FMA. Coalesced partial-C store.
// Handles tokens_per_block in rounds of 32 (LDS sized for 32 tokens).
// ---------------------------------------------------------------------------
__global__ __launch_bounds__(256) void k2_avgp(const float* __restrict__ ws_h,
                                               float* __restrict__ ws_C,
                                               int tokens_per_block) {
  __shared__ __align__(16) float sA[32][2][32];  // [tok][khi&1][khi>>1]
  __shared__ __align__(16) float sB[32][128];    // [tok][klo]
  int t = threadIdx.x;
  int lane = t & 63;
  int wave = t >> 6;
  int c2 = t >> 7;        // khi parity this thread consumes
  int klo = t & 127;      // klo this thread consumes

  float acc[32];
#pragma unroll
  for (int j = 0; j < 32; ++j) acc[j] = 0.f;

  int n0 = blockIdx.x * tokens_per_block;
  for (int base = 0; base < tokens_per_block; base += 32) {
    int cnt = tokens_per_block - base;
    if (cnt > 32) cnt = 32;
    // phase 1: token m handled by wave (m % 4 == wave)
    for (int m = wave; m < cnt; m += 4) {
      int n = n0 + base + m;
      float p[CD], q[CD];
#pragma unroll
      for (int c = 0; c < CD; ++c) {
        float hvv = ws_h[(size_t)n * CD + c];
        float e = expf(-4.f * hvv);
        float r = 1.f / (1.f + e);
        p[c] = r;           // P(bit c = 1)
        q[c] = e * r;       // P(bit c = 0)
      }
      // A over c=0..5; khi = lane, bit c of khi-part = (khi >> (5-c)) & 1
      float A = ((lane >> 5) & 1) ? p[0] : q[0];
      A *= ((lane >> 4) & 1) ? p[1] : q[1];
      A *= ((lane >> 3) & 1) ? p[2] : q[2];
      A *= ((lane >> 2) & 1) ? p[3] : q[3];
      A *= ((lane >> 1) & 1) ? p[4] : q[4];
      A *= (lane & 1) ? p[5] : q[5];
      sA[m][lane & 1][lane >> 1] = A;
      // B over c=6..12; klo = lane (bit6=0 -> q6) and lane+64 (bit6=1 -> p6)
      float Bb = ((lane >> 5) & 1) ? p[7] : q[7];
      Bb *= ((lane >> 4) & 1) ? p[8] : q[8];
      Bb *= ((lane >> 3) & 1) ? p[9] : q[9];
      Bb *= ((lane >> 2) & 1) ? p[10] : q[10];
      Bb *= ((lane >> 1) & 1) ? p[11] : q[11];
      Bb *= (lane & 1) ? p[12] : q[12];
      sB[m][lane] = q[6] * Bb;
      sB[m][64 + lane] = p[6] * Bb;
    }
    __syncthreads();
    // phase 2: accumulate; slot s = t + 256*j -> khi = 2j + c2, klo = t&127
    for (int m = 0; m < cnt; ++m) {
      float Bv = sB[m][klo];
      const float4* A4 = (const float4*)&sA[m][c2][0];
#pragma unroll
      for (int jj = 0; jj < 8; ++jj) {
        float4 a = A4[jj];
        acc[jj * 4 + 0] = fmaf(a.x, Bv, acc[jj * 4 + 0]);
        acc[jj * 4 + 1] = fmaf(a.y, Bv, acc[jj * 4 + 1]);
        acc[jj * 4 + 2] = fmaf(a.z, Bv, acc[jj * 4 + 2]);
        acc[jj * 4 + 3] = fmaf(a.w, Bv, acc[jj * 4 + 3]);
      }
    }
    __syncthreads();
  }

  float* dst = ws_C + (size_t)blockIdx.x * KSZ;
#pragma unroll
  for (int j = 0; j < 32; ++j) dst[t + 256 * j] = acc[j];  // coalesced per j
}

// ---------------------------------------------------------------------------
// K3: reduce nparts partial C's -> per-block entropy partial (plain store).
// 256 blocks x 32 slots each.
// ---------------------------------------------------------------------------
__global__ __launch_bounds__(256) void k3_cbent(const float* __restrict__ ws_C,
                                                float* __restrict__ ws_e,
                                                int nparts) {
  __shared__ float red[256];
  int t = threadIdx.x;
  int sl = t & 31, pg = t >> 5;
  int s = blockIdx.x * 32 + sl;
  float sum = 0.f;
  for (int p = pg; p < nparts; p += 8) sum += ws_C[(size_t)p * KSZ + s];
  red[t] = sum;
  __syncthreads();
  if (t < 64) {
    float contrib = 0.f;
    if (t < 32) {
      float v = red[t];
#pragma unroll
      for (int j = 1; j < 8; ++j) v += red[t + 32 * j];
      float avg = v * (1.f / (float)NTOK);
      contrib = -avg * logf(avg + 1e-5f);
    }
    contrib += __shfl_xor(contrib, 1, 64);
    contrib += __shfl_xor(contrib, 2, 64);
    contrib += __shfl_xor(contrib, 4, 64);
    contrib += __shfl_xor(contrib, 8, 64);
    contrib += __shfl_xor(contrib, 16, 64);
    if (t == 0) ws_e[blockIdx.x] = contrib;
  }
}

// ---------------------------------------------------------------------------
// K4: final assembly (single block, fixed-order deterministic sums).
// ---------------------------------------------------------------------------
__global__ __launch_bounds__(256) void k4_final(const float* __restrict__ ws_pc,
                                                const float* __restrict__ ws_e,
                                                float* __restrict__ d_aux) {
  __shared__ float rc[256], rp[256], re[256];
  int t = threadIdx.x;
  float cm = 0.f, pe = 0.f;
  for (int i = t; i < 512; i += 256) { cm += ws_pc[2 * i]; pe += ws_pc[2 * i + 1]; }
  rc[t] = cm; rp[t] = pe; re[t] = ws_e[t];
  __syncthreads();
  if (t < 64) {
    float C = rc[t] + rc[t + 64] + rc[t + 128] + rc[t + 192];
    float P = rp[t] + rp[t + 64] + rp[t + 128] + rp[t + 192];
    float E = re[t] + re[t + 64] + re[t + 128] + re[t + 192];
    C += __shfl_xor(C, 1, 64); P += __shfl_xor(P, 1, 64); E += __shfl_xor(E, 1, 64);
    C += __shfl_xor(C, 2, 64); P += __shfl_xor(P, 2, 64); E += __shfl_xor(E, 2, 64);
    C += __shfl_xor(C, 4, 64); P += __shfl_xor(P, 4, 64); E += __shfl_xor(E, 4, 64);
    C += __shfl_xor(C, 8, 64); P += __shfl_xor(P, 8, 64); E += __shfl_xor(E, 8, 64);
    C += __shfl_xor(C, 16, 64); P += __shfl_xor(P, 16, 64); E += __shfl_xor(E, 16, 64);
    C += __shfl_xor(C, 32, 64); P += __shfl_xor(P, 32, 64); E += __shfl_xor(E, 32, 64);
    if (t == 0) {
      float commit = C * (1.f / (float)(NTOK * CD));
      float psE = P * (1.f / (float)NTOK);
      d_aux[0] = 0.1f * (psE - E) + 0.25f * commit;
    }
  }
}

extern "C" void kernel_launch(void* const* d_in, const int* in_sizes, int n_in,
                              void* d_out, int out_size, void* d_ws, size_t ws_size,
                              hipStream_t stream) {
  const float* x     = (const float*)d_in[0];
  const float* w_in  = (const float*)d_in[1];
  const float* b_in  = (const float*)d_in[2];
  const float* w_out = (const float*)d_in[3];
  const float* b_out = (const float*)d_in[4];
  // d_in[5] = codebook (unused: codes are the 13-bit sign patterns)

  float* outv = (float*)d_out;                       // [4*2048*512]
  float* ind  = outv + (size_t)NTOK * DIMV;          // [8192] as float
  float* aux  = ind + NTOK;                          // [1]

  float* ws_h  = (float*)d_ws;
  float* ws_pc = (float*)((char*)d_ws + PC_OFF);
  float* ws_e  = (float*)((char*)d_ws + E_OFF);
  float* ws_C  = (float*)((char*)d_ws + C_OFF);

  int nparts = 512;
  while (nparts > 64 && (size_t)C_OFF + (size_t)nparts * KSZ * 4 > ws_size)
    nparts >>= 1;

  k1_fused<<<NTOK / 16, 256, 0, stream>>>(x, w_in, b_in, w_out, b_out,
                                          ws_h, ws_pc, outv, ind);
  k2_avgp<<<nparts, 256, 0, stream>>>(ws_h, ws_C, NTOK / nparts);
  k3_cbent<<<256, 256, 0, stream>>>(ws_C, ws_e, nparts);
  k4_final<<<1, 256, 0, stream>>>(ws_pc, ws_e, aux);
}